// Round 2
// baseline (589.931 us; speedup 1.0000x reference)
//
#include <hip/hip_runtime.h>
#include <hip/hip_bf16.h>
#include <math.h>

// GraphMemory: E=384, columns CW=E*E=147456.
// t[k,c] = x[k] * (space[k,c] + bias[k,c] + (k==c%E)*kernel[k,c]*x[c/E]/sqrt2)
// out[k] = max_c softmax_k(t[:,c])[k] = exp(max_c (t[k,c] - logsumexp_k t[k,c]))
//
// R2 design: register-resident, zero LDS tile. WG = 16 columns x 384 rows.
// Thread (g=t&3, rb=t>>2) owns cols 4g..4g+3 and rows rb+64q (q<6): 24 vals
// in VGPRs. Column sum-of-exp via shfl stride-4; row max via shfl 1,2 over
// the 4 consecutive lanes sharing a row. |t| << 1 so no max-subtract needed.

#define E    384
#define CW   (E * E)          // 147456
#define CB   16               // columns per workgroup
#define NWG  (CW / CB)        // 9216
#define RPT  6                // rows per thread (384 / 64)
#define WB   36               // reduce1 w-tiles (36*256 = 9216)
#define KB   6                // reduce1 k-tiles (6*64 = 384)

__device__ __forceinline__ unsigned enc_f32(float v) {
    unsigned u = __float_as_uint(v);
    return (u & 0x80000000u) ? ~u : (u | 0x80000000u);
}
__device__ __forceinline__ float dec_f32(unsigned e) {
    unsigned u = (e & 0x80000000u) ? (e ^ 0x80000000u) : ~e;
    return __uint_as_float(u);
}

__global__ __launch_bounds__(256, 6) void gm_main(
    const float* __restrict__ x, const float* __restrict__ kern,
    const float* __restrict__ bias, const float* __restrict__ space,
    float* __restrict__ pw, unsigned* __restrict__ aws, int use_atomic)
{
    __shared__ float ps[4][CB];   // per-wave column exp-sums
    __shared__ float Lc[CB];      // per-column logsumexp

    const int t   = threadIdx.x;
    const int wg  = blockIdx.x;
    const int c0  = wg * CB;
    const int j   = c0 / E;       // all 16 cols share j (16 | 384)
    const int ls  = c0 % E;
    const int g   = t & 3;
    const int rb  = t >> 2;
    const int cbase = c0 + 4 * g;
    const float xj = x[j] * 0.70710678118654752440f;

    float val[RPT][4];
    float s0 = 0.f, s1 = 0.f, s2 = 0.f, s3 = 0.f;

    #pragma unroll
    for (int ch = 0; ch < 2; ++ch) {
        float4 b4[3], p4[3];
        float  xr[3];
        #pragma unroll
        for (int q = 0; q < 3; ++q) {
            const int r    = rb + 64 * (3 * ch + q);
            const int base = r * CW + cbase;
            b4[q] = *(const float4*)(bias  + base);
            p4[q] = *(const float4*)(space + base);
            xr[q] = x[r];
        }
        #pragma unroll
        for (int q = 0; q < 3; ++q) {
            const int qq = 3 * ch + q;
            const int r  = rb + 64 * qq;
            float v0 = b4[q].x + p4[q].x;
            float v1 = b4[q].y + p4[q].y;
            float v2 = b4[q].z + p4[q].z;
            float v3 = b4[q].w + p4[q].w;
            const int cl = r - ls - 4 * g;   // diag col within my 4, if any
            if (cl >= 0 && cl < 4) {
                const float kd = kern[r * CW + cbase + cl] * xj;
                if      (cl == 0) v0 += kd;
                else if (cl == 1) v1 += kd;
                else if (cl == 2) v2 += kd;
                else              v3 += kd;
            }
            v0 *= xr[q]; v1 *= xr[q]; v2 *= xr[q]; v3 *= xr[q];
            val[qq][0] = v0; val[qq][1] = v1;
            val[qq][2] = v2; val[qq][3] = v3;
            s0 += __expf(v0); s1 += __expf(v1);
            s2 += __expf(v2); s3 += __expf(v3);
        }
    }

    // column sums: reduce over rb within wave (lanes stride 4)
    #pragma unroll
    for (int m = 4; m <= 32; m <<= 1) {
        s0 += __shfl_xor(s0, m, 64);
        s1 += __shfl_xor(s1, m, 64);
        s2 += __shfl_xor(s2, m, 64);
        s3 += __shfl_xor(s3, m, 64);
    }
    const int wave = t >> 6;
    if ((t & 63) < 4) {           // lane index == g for these lanes
        ps[wave][4 * g + 0] = s0;
        ps[wave][4 * g + 1] = s1;
        ps[wave][4 * g + 2] = s2;
        ps[wave][4 * g + 3] = s3;
    }
    __syncthreads();
    if (t < CB)
        Lc[t] = __logf(ps[0][t] + ps[1][t] + ps[2][t] + ps[3][t]);
    __syncthreads();

    const float l0 = Lc[4 * g + 0], l1 = Lc[4 * g + 1];
    const float l2 = Lc[4 * g + 2], l3 = Lc[4 * g + 3];
    #pragma unroll
    for (int qq = 0; qq < RPT; ++qq) {
        float rm = fmaxf(fmaxf(val[qq][0] - l0, val[qq][1] - l1),
                         fmaxf(val[qq][2] - l2, val[qq][3] - l3));
        rm = fmaxf(rm, __shfl_xor(rm, 1, 64));
        rm = fmaxf(rm, __shfl_xor(rm, 2, 64));
        if (g == 0) {
            const int r = rb + 64 * qq;
            if (use_atomic) atomicMax(aws + r, enc_f32(rm));
            else            pw[wg * E + r] = rm;
        }
    }
}

// reduce1: pw[9216][384] -> pw2[36][384]
__global__ __launch_bounds__(256) void gm_reduce1(
    const float* __restrict__ pw, float* __restrict__ pw2)
{
    __shared__ float sm[256];
    const int t  = threadIdx.x;
    const int kb = blockIdx.x % KB;
    const int wb = blockIdx.x / KB;
    const int k  = kb * 64 + (t & 63);
    const int wl = t >> 6;
    float mx = -INFINITY;
    for (int w = wb * 256 + wl; w < wb * 256 + 256; w += 4)
        mx = fmaxf(mx, pw[w * E + k]);
    sm[t] = mx;
    __syncthreads();
    if (t < 64) {
        mx = fmaxf(fmaxf(sm[t], sm[t + 64]), fmaxf(sm[t + 128], sm[t + 192]));
        pw2[wb * E + kb * 64 + t] = mx;
    }
}

// reduce2: pw2[36][384] -> out[384]
__global__ __launch_bounds__(384) void gm_reduce2(
    const float* __restrict__ pw2, float* __restrict__ out)
{
    const int k = threadIdx.x;
    float mx = -INFINITY;
    #pragma unroll
    for (int wb = 0; wb < WB; ++wb)
        mx = fmaxf(mx, pw2[wb * E + k]);
    out[k] = expf(mx);
}

__global__ __launch_bounds__(384) void gm_final_atomic(
    const unsigned* __restrict__ aws, float* __restrict__ out)
{
    const int k = threadIdx.x;
    out[k] = expf(dec_f32(aws[k]));
}

extern "C" void kernel_launch(void* const* d_in, const int* in_sizes, int n_in,
                              void* d_out, int out_size, void* d_ws, size_t ws_size,
                              hipStream_t stream)
{
    const float* x     = (const float*)d_in[0];
    const float* kern  = (const float*)d_in[1];
    const float* bias  = (const float*)d_in[2];
    const float* space = (const float*)d_in[3];
    float* out = (float*)d_out;

    const size_t pw_elems = (size_t)NWG * E;
    const size_t need = (pw_elems + (size_t)WB * E) * sizeof(float);

    if (ws_size >= need) {
        float* pw  = (float*)d_ws;
        float* pw2 = pw + pw_elems;
        gm_main<<<NWG, 256, 0, stream>>>(x, kern, bias, space, pw, nullptr, 0);
        gm_reduce1<<<KB * WB, 256, 0, stream>>>(pw, pw2);
        gm_reduce2<<<1, 384, 0, stream>>>(pw2, out);
    } else {
        unsigned* aws = (unsigned*)d_ws;
        hipMemsetAsync(aws, 0, E * sizeof(unsigned), stream);
        gm_main<<<NWG, 256, 0, stream>>>(x, kern, bias, space, nullptr, aws, 1);
        gm_final_atomic<<<1, 384, 0, stream>>>(aws, out);
    }
}

// Round 3
// 579.838 us; speedup vs baseline: 1.0174x; 1.0174x over previous
//
#include <hip/hip_runtime.h>
#include <hip/hip_bf16.h>
#include <hip/hip_fp16.h>
#include <math.h>

// GraphMemory: E=384, columns CW=E*E=147456.
// t[k,c] = x[k] * (space[k,c] + bias[k,c] + (k==c%E)*kernel[k,c]*x[c/E]/sqrt2)
// out[k] = max_c softmax_k(t[:,c])[k] = max_c exp(t[k,c]) / S[c],  S[c]=sum_k exp(t[k,c])
//
// R3: row-major streaming (1KB contiguous per wave instr) in two passes,
// fp16 intermediate e=exp(t) (113MB) through HBM. Avoids the 64B-granule
// 576KB-stride pattern that capped R1/R2 at ~2.5 TB/s.

#define E    384
#define CW   (E * E)            // 147456

// pass1: 32 rows x 1024 cols per WG
#define RB1  32
#define CC1  1024
#define NKB1 (E / RB1)          // 12
#define NCB1 (CW / CC1)         // 144
// pass2: 32 rows x 2048 cols per WG
#define RB2  32
#define CC2  2048
#define NKB2 (E / RB2)          // 12
#define NCB2 (CW / CC2)         // 72

// fallback (R2 design)
#define CBF  16
#define NWGF (CW / CBF)         // 9216
#define RPTF 6
#define WBF  36
#define KBF  6

__device__ __forceinline__ unsigned enc_f32(float v) {
    unsigned u = __float_as_uint(v);
    return (u & 0x80000000u) ? ~u : (u | 0x80000000u);
}
__device__ __forceinline__ float dec_f32(unsigned e) {
    unsigned u = (e & 0x80000000u) ? (e ^ 0x80000000u) : ~e;
    return __uint_as_float(u);
}

// ---------------- pass 1: stream rows, write e (fp16), partial col sums ----
__global__ __launch_bounds__(256) void gm_pass1(
    const float* __restrict__ x, const float* __restrict__ kern,
    const float* __restrict__ bias, const float* __restrict__ space,
    float2* __restrict__ e4,          // fp16 e, 4 halfs per float2 slot
    float* __restrict__ Sp)           // [NKB1][CW] partial sums
{
    const int t  = threadIdx.x;
    const int cb = blockIdx.x % NCB1;   // adjacent blocks -> adjacent columns
    const int kb = blockIdx.x / NCB1;
    const int c  = cb * CC1 + 4 * t;    // 4 consecutive cols per thread
    const int m  = c % E;               // no wrap within the 4 (4 | E)
    const int j  = c / E;               // shared by the 4 cols
    const float xj = x[j] * 0.70710678118654752440f;
    const int k0 = kb * RB1;

    float s0 = 0.f, s1 = 0.f, s2 = 0.f, s3 = 0.f;

    for (int rr = 0; rr < RB1; rr += 4) {
        float4 b4[4], p4[4];
        #pragma unroll
        for (int u = 0; u < 4; ++u) {
            const int k   = k0 + rr + u;
            const int off = k * CW + c;
            b4[u] = *(const float4*)(bias  + off);
            p4[u] = *(const float4*)(space + off);
        }
        #pragma unroll
        for (int u = 0; u < 4; ++u) {
            const int k = k0 + rr + u;
            float v0 = b4[u].x + p4[u].x;
            float v1 = b4[u].y + p4[u].y;
            float v2 = b4[u].z + p4[u].z;
            float v3 = b4[u].w + p4[u].w;
            const int dl = k - m;               // diag hit if 0..3
            if ((unsigned)dl < 4u) {
                const float kd = kern[k * CW + c + dl] * xj;
                if      (dl == 0) v0 += kd;
                else if (dl == 1) v1 += kd;
                else if (dl == 2) v2 += kd;
                else              v3 += kd;
            }
            const float xk = x[k];              // wave-uniform -> scalar
            v0 *= xk; v1 *= xk; v2 *= xk; v3 *= xk;
            const float e0 = __expf(v0), e1 = __expf(v1);
            const float e2 = __expf(v2), e3 = __expf(v3);
            s0 += e0; s1 += e1; s2 += e2; s3 += e3;
            union { __half2 h[2]; float2 f; } pk;
            pk.h[0] = __floats2half2_rn(e0, e1);
            pk.h[1] = __floats2half2_rn(e2, e3);
            e4[(k * CW + c) >> 2] = pk.f;       // 8B store, aligned
        }
    }
    *(float4*)(Sp + kb * CW + c) = make_float4(s0, s1, s2, s3);
}

// ---------------- mid: R[c] = 1 / sum_kb Sp[kb][c] ----------------
__global__ __launch_bounds__(256) void gm_inv(
    const float* __restrict__ Sp, float* __restrict__ R)
{
    const int c = 4 * (blockIdx.x * 256 + threadIdx.x);
    float4 a = *(const float4*)(Sp + c);
    #pragma unroll
    for (int kb = 1; kb < NKB1; ++kb) {
        const float4 b = *(const float4*)(Sp + kb * CW + c);
        a.x += b.x; a.y += b.y; a.z += b.z; a.w += b.w;
    }
    *(float4*)(R + c) = make_float4(1.f / a.x, 1.f / a.y, 1.f / a.z, 1.f / a.w);
}

// ---------------- pass 2: out-partials = per-row max of e*R --------------
__global__ __launch_bounds__(256) void gm_pass2(
    const float4* __restrict__ e8,    // fp16 e, 8 halfs per float4 slot
    const float* __restrict__ R,
    float* __restrict__ pw)           // [NCB2][E]
{
    __shared__ float pm[4][RB2];
    const int t  = threadIdx.x;
    const int cb = blockIdx.x % NCB2;
    const int kb = blockIdx.x / NCB2;
    const int c  = cb * CC2 + 8 * t;
    const int k0 = kb * RB2;
    const int wave = t >> 6;
    const int lane = t & 63;
    const float4 ra = *(const float4*)(R + c);
    const float4 rb = *(const float4*)(R + c + 4);

    for (int rr = 0; rr < RB2; rr += 4) {
        float4 ev[4];
        #pragma unroll
        for (int u = 0; u < 4; ++u) {
            const int k = k0 + rr + u;
            ev[u] = e8[(k * CW + c) >> 3];
        }
        float mx[4];
        #pragma unroll
        for (int u = 0; u < 4; ++u) {
            const __half2* h = (const __half2*)&ev[u];
            const float2 f0 = __half22float2(h[0]);
            const float2 f1 = __half22float2(h[1]);
            const float2 f2 = __half22float2(h[2]);
            const float2 f3 = __half22float2(h[3]);
            const float a0 = fmaxf(f0.x * ra.x, f0.y * ra.y);
            const float a1 = fmaxf(f1.x * ra.z, f1.y * ra.w);
            const float a2 = fmaxf(f2.x * rb.x, f2.y * rb.y);
            const float a3 = fmaxf(f3.x * rb.z, f3.y * rb.w);
            mx[u] = fmaxf(fmaxf(a0, a1), fmaxf(a2, a3));
        }
        #pragma unroll
        for (int st = 1; st < 64; st <<= 1) {
            mx[0] = fmaxf(mx[0], __shfl_xor(mx[0], st, 64));
            mx[1] = fmaxf(mx[1], __shfl_xor(mx[1], st, 64));
            mx[2] = fmaxf(mx[2], __shfl_xor(mx[2], st, 64));
            mx[3] = fmaxf(mx[3], __shfl_xor(mx[3], st, 64));
        }
        if (lane == 0) {
            pm[wave][rr + 0] = mx[0]; pm[wave][rr + 1] = mx[1];
            pm[wave][rr + 2] = mx[2]; pm[wave][rr + 3] = mx[3];
        }
    }
    __syncthreads();
    if (t < RB2) {
        const float v = fmaxf(fmaxf(pm[0][t], pm[1][t]),
                              fmaxf(pm[2][t], pm[3][t]));
        pw[cb * E + k0 + t] = v;
    }
}

// ---------------- final: out[k] = max_cb pw[cb][k] ----------------
__global__ __launch_bounds__(384) void gm_out(
    const float* __restrict__ pw, float* __restrict__ out)
{
    const int k = threadIdx.x;
    float mx = -INFINITY;
    #pragma unroll
    for (int cb = 0; cb < NCB2; ++cb)
        mx = fmaxf(mx, pw[cb * E + k]);
    out[k] = mx;    // already exp(t)/S == softmax value
}

// ================= fallback (R2 design, ws-light) =================
__global__ __launch_bounds__(256, 6) void gm_main_fb(
    const float* __restrict__ x, const float* __restrict__ kern,
    const float* __restrict__ bias, const float* __restrict__ space,
    float* __restrict__ pw, unsigned* __restrict__ aws, int use_atomic)
{
    __shared__ float ps[4][CBF];
    __shared__ float Lc[CBF];
    const int t   = threadIdx.x;
    const int wg  = blockIdx.x;
    const int c0  = wg * CBF;
    const int j   = c0 / E;
    const int ls  = c0 % E;
    const int g   = t & 3;
    const int rb  = t >> 2;
    const int cbase = c0 + 4 * g;
    const float xj = x[j] * 0.70710678118654752440f;

    float val[RPTF][4];
    float s0 = 0.f, s1 = 0.f, s2 = 0.f, s3 = 0.f;
    #pragma unroll
    for (int qq = 0; qq < RPTF; ++qq) {
        const int r    = rb + 64 * qq;
        const int base = r * CW + cbase;
        const float4 b4 = *(const float4*)(bias  + base);
        const float4 p4 = *(const float4*)(space + base);
        float v0 = b4.x + p4.x, v1 = b4.y + p4.y;
        float v2 = b4.z + p4.z, v3 = b4.w + p4.w;
        const int cl = r - ls - 4 * g;
        if (cl >= 0 && cl < 4) {
            const float kd = kern[r * CW + cbase + cl] * xj;
            if      (cl == 0) v0 += kd;
            else if (cl == 1) v1 += kd;
            else if (cl == 2) v2 += kd;
            else              v3 += kd;
        }
        const float xr = x[r];
        v0 *= xr; v1 *= xr; v2 *= xr; v3 *= xr;
        val[qq][0] = v0; val[qq][1] = v1; val[qq][2] = v2; val[qq][3] = v3;
        s0 += __expf(v0); s1 += __expf(v1); s2 += __expf(v2); s3 += __expf(v3);
    }
    #pragma unroll
    for (int mk = 4; mk <= 32; mk <<= 1) {
        s0 += __shfl_xor(s0, mk, 64); s1 += __shfl_xor(s1, mk, 64);
        s2 += __shfl_xor(s2, mk, 64); s3 += __shfl_xor(s3, mk, 64);
    }
    const int wave = t >> 6;
    if ((t & 63) < 4) {
        ps[wave][4 * g + 0] = s0; ps[wave][4 * g + 1] = s1;
        ps[wave][4 * g + 2] = s2; ps[wave][4 * g + 3] = s3;
    }
    __syncthreads();
    if (t < CBF) Lc[t] = __logf(ps[0][t] + ps[1][t] + ps[2][t] + ps[3][t]);
    __syncthreads();
    const float l0 = Lc[4 * g + 0], l1 = Lc[4 * g + 1];
    const float l2 = Lc[4 * g + 2], l3 = Lc[4 * g + 3];
    #pragma unroll
    for (int qq = 0; qq < RPTF; ++qq) {
        float rm = fmaxf(fmaxf(val[qq][0] - l0, val[qq][1] - l1),
                         fmaxf(val[qq][2] - l2, val[qq][3] - l3));
        rm = fmaxf(rm, __shfl_xor(rm, 1, 64));
        rm = fmaxf(rm, __shfl_xor(rm, 2, 64));
        if (g == 0) {
            const int r = rb + 64 * qq;
            if (use_atomic) atomicMax(aws + r, enc_f32(rm));
            else            pw[wg * E + r] = rm;
        }
    }
}

__global__ __launch_bounds__(256) void gm_reduce1_fb(
    const float* __restrict__ pw, float* __restrict__ pw2)
{
    __shared__ float sm[256];
    const int t  = threadIdx.x;
    const int kb = blockIdx.x % KBF;
    const int wb = blockIdx.x / KBF;
    const int k  = kb * 64 + (t & 63);
    const int wl = t >> 6;
    float mx = -INFINITY;
    for (int w = wb * 256 + wl; w < wb * 256 + 256; w += 4)
        mx = fmaxf(mx, pw[w * E + k]);
    sm[t] = mx;
    __syncthreads();
    if (t < 64) {
        mx = fmaxf(fmaxf(sm[t], sm[t + 64]), fmaxf(sm[t + 128], sm[t + 192]));
        pw2[wb * E + kb * 64 + t] = mx;
    }
}

__global__ __launch_bounds__(384) void gm_reduce2_fb(
    const float* __restrict__ pw2, float* __restrict__ out)
{
    const int k = threadIdx.x;
    float mx = -INFINITY;
    #pragma unroll
    for (int wb = 0; wb < WBF; ++wb)
        mx = fmaxf(mx, pw2[wb * E + k]);
    out[k] = expf(mx);
}

__global__ __launch_bounds__(384) void gm_final_atomic(
    const unsigned* __restrict__ aws, float* __restrict__ out)
{
    const int k = threadIdx.x;
    out[k] = expf(dec_f32(aws[k]));
}

extern "C" void kernel_launch(void* const* d_in, const int* in_sizes, int n_in,
                              void* d_out, int out_size, void* d_ws, size_t ws_size,
                              hipStream_t stream)
{
    const float* x     = (const float*)d_in[0];
    const float* kern  = (const float*)d_in[1];
    const float* bias  = (const float*)d_in[2];
    const float* space = (const float*)d_in[3];
    float* out = (float*)d_out;

    const size_t e_bytes  = (size_t)E * CW * 2;            // 113.2 MB fp16
    const size_t sp_bytes = (size_t)NKB1 * CW * 4;         // 7.08 MB
    const size_t r_bytes  = (size_t)CW * 4;                // 0.59 MB
    const size_t pw_bytes = (size_t)NCB2 * E * 4;          // 0.11 MB
    const size_t need_main = e_bytes + sp_bytes + r_bytes + pw_bytes;
    const size_t need_fb = ((size_t)NWGF * E + (size_t)WBF * E) * 4;

    if (ws_size >= need_main) {
        char* w = (char*)d_ws;
        float2* e4 = (float2*)w;
        float*  Sp = (float*)(w + e_bytes);
        float*  R  = (float*)(w + e_bytes + sp_bytes);
        float*  pw = (float*)(w + e_bytes + sp_bytes + r_bytes);
        gm_pass1<<<NKB1 * NCB1, 256, 0, stream>>>(x, kern, bias, space, e4, Sp);
        gm_inv<<<CW / (256 * 4), 256, 0, stream>>>(Sp, R);
        gm_pass2<<<NKB2 * NCB2, 256, 0, stream>>>((const float4*)e4, R, pw);
        gm_out<<<1, 384, 0, stream>>>(pw, out);
    } else if (ws_size >= need_fb) {
        float* pw  = (float*)d_ws;
        float* pw2 = pw + (size_t)NWGF * E;
        gm_main_fb<<<NWGF, 256, 0, stream>>>(x, kern, bias, space, pw, nullptr, 0);
        gm_reduce1_fb<<<KBF * WBF, 256, 0, stream>>>(pw, pw2);
        gm_reduce2_fb<<<1, 384, 0, stream>>>(pw2, out);
    } else {
        unsigned* aws = (unsigned*)d_ws;
        hipMemsetAsync(aws, 0, E * sizeof(unsigned), stream);
        gm_main_fb<<<NWGF, 256, 0, stream>>>(x, kern, bias, space, nullptr, aws, 1);
        gm_final_atomic<<<1, 384, 0, stream>>>(aws, out);
    }
}